// Round 3
// baseline (160.499 us; speedup 1.0000x reference)
//
#include <hip/hip_runtime.h>

// Problem constants (fixed by the reference).
constexpr int N_SAE  = 128;
constexpr int D_DATA = 128;
constexpr int D_DICT = 512;
constexpr int B_TOK  = 1024;

constexpr int SPLIT  = 4;                 // token split (t mod 4)
constexpr int NCHUNK = 4;                 // dict-dim split
constexpr int CW     = D_DICT / NCHUNK;   // 128 dict cols per chunk
constexpr int TILE_T = 8;                 // tokens per tile (avg 4 per block)
constexpr int NT     = 256;               // threads per block
constexpr int CAP    = 64;                // max pairs per (expert, quarter); mean 4, P(>64)~0

// ---- Routing precompute: coalesced scan of gate, bucket into (expert, quarter) lists ----
__global__ __launch_bounds__(NT)
void route_kernel(const float* __restrict__ gate,
                  int* __restrict__ counts,     // [N_SAE*SPLIT]
                  int* __restrict__ toks,       // [N_SAE*SPLIT][CAP]
                  float* __restrict__ gvs)      // [N_SAE*SPLIT][CAP]
{
    const int t = blockIdx.x * 2 + (threadIdx.x >> 7);   // 512 blocks x 2 tokens
    const int e = threadIdx.x & 127;
    float g = gate[(size_t)t * N_SAE + e];               // fully coalesced
    if (g != 0.0f) {
        int idx  = e * SPLIT + (t & (SPLIT - 1));
        int slot = atomicAdd(&counts[idx], 1);
        if (slot < CAP) {
            toks[idx * CAP + slot] = t;
            gvs[idx * CAP + slot]  = g;
        }
    }
}

__global__ __launch_bounds__(NT)
void moe_sae_kernel(const float* __restrict__ x,
                    const float* __restrict__ gate,
                    const float* __restrict__ W_enc,
                    const float* __restrict__ W_dec,
                    const float* __restrict__ b_enc,
                    const float* __restrict__ b_dec,
                    float* __restrict__ out,
                    const int* __restrict__ counts,
                    const int* __restrict__ toks,
                    const float* __restrict__ gvs,
                    int use_route)
{
    const int e   = blockIdx.x;   // expert id
    const int c   = blockIdx.y;   // dict chunk id
    const int h   = blockIdx.z;   // token quarter
    const int tid = threadIdx.x;
    const int c0  = c * CW;

    __shared__ int   s_tok[CAP];
    __shared__ float s_g[CAP];
    __shared__ int   s_count;
    __shared__ float s_x[TILE_T][D_DATA];   // 4 KB
    __shared__ float s_acts[TILE_T][CW];    // 4 KB

    int n;
    if (use_route) {
        const int idx = e * SPLIT + h;
        n = min(counts[idx], CAP);
        if (tid < n) {
            s_tok[tid] = toks[idx * CAP + tid];
            s_g[tid]   = gvs[idx * CAP + tid];
        }
        __syncthreads();
    } else {
        if (tid == 0) s_count = 0;
        __syncthreads();
        for (int i = tid; i < B_TOK / SPLIT; i += NT) {
            int t = i * SPLIT + h;
            float gv = gate[(size_t)t * N_SAE + e];
            if (gv != 0.0f) {
                int slot = atomicAdd(&s_count, 1);
                if (slot < CAP) { s_tok[slot] = t; s_g[slot] = gv; }
            }
        }
        __syncthreads();
        n = min(s_count, CAP);
    }
    if (n == 0) return;

    const float*  We  = W_enc + (size_t)e * D_DATA * D_DICT;                  // [128][512]
    const float2* Wd2 = (const float2*)(W_dec + (size_t)e * D_DICT * D_DATA); // [512][64 f2]

    // encode mapping: col = c0 + (tid&127); tg = tid>>7 owns 4 tokens
    const int ecol = tid & (CW - 1);
    const int tg   = tid >> 7;
    const float be = b_enc[(size_t)e * D_DICT + c0 + ecol];

    // decode mapping: dp = tid&63 -> out cols (2dp, 2dp+1); hh = tid>>6 owns tokens {hh, hh+4}
    const int dp = tid & 63;
    const int hh = tid >> 6;
    const float2 bd = ((const float2*)(b_dec + (size_t)e * D_DATA))[dp];

    for (int t0 = 0; t0 < n; t0 += TILE_T) {
        const int tcnt = min(TILE_T, n - t0);

        // ---- load x tile (coalesced float4; 1 iter/thread) ----
        for (int i = tid; i < tcnt * (D_DATA / 4); i += NT) {
            int tt = i >> 5;          // / 32
            int dd = i & 31;          // % 32
            ((float4*)s_x[tt])[dd] =
                ((const float4*)(x + (size_t)s_tok[t0 + tt] * D_DATA))[dd];
        }
        __syncthreads();

        // ---- encode: thread owns dict col (c0+ecol), tokens tg*4..tg*4+3 ----
        {
            float acc[4];
            #pragma unroll
            for (int j = 0; j < 4; ++j) acc[j] = be;
            #pragma unroll 2
            for (int d = 0; d < D_DATA; d += 4) {
                float w0 = We[(size_t)(d + 0) * D_DICT + c0 + ecol];
                float w1 = We[(size_t)(d + 1) * D_DICT + c0 + ecol];
                float w2 = We[(size_t)(d + 2) * D_DICT + c0 + ecol];
                float w3 = We[(size_t)(d + 3) * D_DICT + c0 + ecol];
                #pragma unroll
                for (int j = 0; j < 4; ++j) {
                    float4 xv = *(const float4*)&s_x[tg * 4 + j][d];  // broadcast
                    acc[j] = fmaf(xv.x, w0, acc[j]);
                    acc[j] = fmaf(xv.y, w1, acc[j]);
                    acc[j] = fmaf(xv.z, w2, acc[j]);
                    acc[j] = fmaf(xv.w, w3, acc[j]);
                }
            }
            #pragma unroll
            for (int j = 0; j < 4; ++j) {
                int t = tg * 4 + j;
                if (t < tcnt) s_acts[t][ecol] = fmaxf(acc[j], 0.0f) * s_g[t0 + t];
            }
        }
        __syncthreads();

        // ---- decode (partial over this chunk's 128 dict rows) ----
        {
            float accA[2], accB[2];
            #pragma unroll
            for (int j = 0; j < 2; ++j) { accA[j] = 0.0f; accB[j] = 0.0f; }
            #pragma unroll 2
            for (int ee = 0; ee < CW; ee += 4) {
                float2 w0 = Wd2[(size_t)(c0 + ee + 0) * (D_DATA / 2) + dp];
                float2 w1 = Wd2[(size_t)(c0 + ee + 1) * (D_DATA / 2) + dp];
                float2 w2 = Wd2[(size_t)(c0 + ee + 2) * (D_DATA / 2) + dp];
                float2 w3 = Wd2[(size_t)(c0 + ee + 3) * (D_DATA / 2) + dp];
                #pragma unroll
                for (int j = 0; j < 2; ++j) {
                    float4 av = *(const float4*)&s_acts[4 * j + hh][ee];  // broadcast
                    accA[j] = fmaf(av.x, w0.x, accA[j]); accB[j] = fmaf(av.x, w0.y, accB[j]);
                    accA[j] = fmaf(av.y, w1.x, accA[j]); accB[j] = fmaf(av.y, w1.y, accB[j]);
                    accA[j] = fmaf(av.z, w2.x, accA[j]); accB[j] = fmaf(av.z, w2.y, accB[j]);
                    accA[j] = fmaf(av.w, w3.x, accA[j]); accB[j] = fmaf(av.w, w3.y, accB[j]);
                }
            }
            #pragma unroll
            for (int j = 0; j < 2; ++j) {
                int t = 4 * j + hh;
                if (t < tcnt) {
                    float* op = out + (size_t)s_tok[t0 + t] * D_DATA + 2 * dp;
                    // b_dec added exactly once per (token, expert): by chunk 0
                    atomicAdd(op,     accA[j] + (c == 0 ? bd.x : 0.0f));
                    atomicAdd(op + 1, accB[j] + (c == 0 ? bd.y : 0.0f));
                }
            }
        }
        __syncthreads();
    }
}

extern "C" void kernel_launch(void* const* d_in, const int* in_sizes, int n_in,
                              void* d_out, int out_size, void* d_ws, size_t ws_size,
                              hipStream_t stream) {
    const float* x     = (const float*)d_in[0];
    const float* gate  = (const float*)d_in[1];
    const float* W_enc = (const float*)d_in[2];
    const float* W_dec = (const float*)d_in[3];
    const float* b_enc = (const float*)d_in[4];
    const float* b_dec = (const float*)d_in[5];
    float* out = (float*)d_out;

    // ws layout: counts[512] int | toks[512*CAP] int | gvs[512*CAP] float
    const size_t n_lists   = (size_t)N_SAE * SPLIT;
    const size_t ws_needed = n_lists * sizeof(int)
                           + n_lists * CAP * (sizeof(int) + sizeof(float));
    int use_route = (ws_size >= ws_needed) ? 1 : 0;

    int*   counts = (int*)d_ws;
    int*   toks   = counts + n_lists;
    float* gvs    = (float*)(toks + n_lists * CAP);

    // d_out is poisoned (0xAA) before every timed launch; we accumulate into it.
    hipMemsetAsync(d_out, 0, (size_t)out_size * sizeof(float), stream);

    if (use_route) {
        hipMemsetAsync(counts, 0, n_lists * sizeof(int), stream);
        route_kernel<<<B_TOK / 2, NT, 0, stream>>>(gate, counts, toks, gvs);
    }

    dim3 grid(N_SAE, NCHUNK, SPLIT);
    moe_sae_kernel<<<grid, NT, 0, stream>>>(x, gate, W_enc, W_dec, b_enc, b_dec, out,
                                            counts, toks, gvs, use_route);
}

// Round 5
// 146.853 us; speedup vs baseline: 1.0929x; 1.0929x over previous
//
#include <hip/hip_runtime.h>
#include <stdint.h>

// Problem constants (fixed by the reference).
constexpr int N_SAE  = 128;
constexpr int D_DATA = 128;
constexpr int D_DICT = 512;
constexpr int B_TOK  = 1024;

constexpr int NCHUNK = 8;                // dict-dim chunks per expert (SPLIT=1 over tokens!)
constexpr int CW     = D_DICT / NCHUNK;  // 64 dict cols/rows per chunk
constexpr int NT     = 256;              // threads per block
constexpr int TILE_T = 16;               // tokens per tile
constexpr int CAP    = 64;               // max tokens per expert (mean 16, P(>64) ~ 0)
constexpr int XPITCH = 33;               // float4 pitch of padded x rows (128 floats -> 33 f4)

// NOTE: must be a function, not a macro — a macro param named `w` would be
// substituted inside `acc.w` by the preprocessor (round-4 compile failure).
__device__ __forceinline__ void fma4(float4& acc, float s, float4 v) {
    acc.x = fmaf(s, v.x, acc.x);
    acc.y = fmaf(s, v.y, acc.y);
    acc.z = fmaf(s, v.z, acc.z);
    acc.w = fmaf(s, v.w, acc.w);
}

__device__ inline void dma16(const float* src, float* lds) {
    __builtin_amdgcn_global_load_lds(
        (const __attribute__((address_space(1))) uint32_t*)src,
        (__attribute__((address_space(3))) uint32_t*)lds, 16, 0, 0);
}

// ---- Routing precompute: coalesced gate scan -> per-expert token lists ----
__global__ __launch_bounds__(NT)
void route_kernel(const float* __restrict__ gate,
                  int* __restrict__ counts,   // [N_SAE]
                  int* __restrict__ toks,     // [N_SAE][CAP]
                  float* __restrict__ gvs)    // [N_SAE][CAP]
{
    const int t = blockIdx.x * 2 + (threadIdx.x >> 7);
    const int e = threadIdx.x & 127;
    float g = gate[(size_t)t * N_SAE + e];    // fully coalesced
    if (g != 0.0f) {
        int slot = atomicAdd(&counts[e], 1);
        if (slot < CAP) {
            toks[e * CAP + slot] = t;
            gvs[e * CAP + slot]  = g;
        }
    }
}

__global__ __launch_bounds__(NT, 2)   // 2 blocks/CU (LDS-limited anyway)
void moe_sae_kernel(const float* __restrict__ x,
                    const float* __restrict__ gate,
                    const float* __restrict__ W_enc,
                    const float* __restrict__ W_dec,
                    const float* __restrict__ b_enc,
                    const float* __restrict__ b_dec,
                    float* __restrict__ out,
                    const int* __restrict__ counts,
                    const int* __restrict__ toks,
                    const float* __restrict__ gvs,
                    int use_route)
{
    const int e    = blockIdx.x;     // expert
    const int c    = blockIdx.y;     // dict chunk
    const int tid  = threadIdx.x;
    const int lane = tid & 63;
    const int wave = tid >> 6;

    __shared__ float s_We[D_DATA * CW];          // [d][64]      32 KB
    __shared__ float s_Wd[CW * D_DATA];          // [row][128]   32 KB
    __shared__ float s_x[TILE_T * XPITCH * 4];   // padded x tile (aliased as partial buf) 8.25 KB
    __shared__ float s_acts[TILE_T * CW];        // 4 KB
    __shared__ int   s_tok[CAP];
    __shared__ float s_g[CAP];
    __shared__ int   s_count;

    // ---- Issue weight DMA first (async, latency-tolerant). 64 KB total ----
    {
        const float* Weg = W_enc + (size_t)e * D_DATA * D_DICT + c * CW;
        for (int j = wave; j < 32; j += 4) {   // each call: 4 rows x 64 cols = 1 KB
            const float* src = Weg + (size_t)(4 * j + (lane >> 4)) * D_DICT + (lane & 15) * 4;
            dma16(src, s_We + j * 256);        // LDS dest = base + lane*16B
        }
        const float* Wdg = W_dec + (size_t)e * D_DICT * D_DATA + (size_t)c * CW * D_DATA;
        for (int j = wave; j < 32; j += 4) {   // contiguous 32 KB stream
            const float* src = Wdg + j * 256 + lane * 4;
            dma16(src, s_Wd + j * 256);
        }
    }

    // ---- Routing lists (overlaps with DMA in flight) ----
    int n;
    if (use_route) {
        n = min(counts[e], CAP);
        if (tid < n) {
            s_tok[tid] = toks[e * CAP + tid];
            s_g[tid]   = gvs[e * CAP + tid];
        }
        __syncthreads();                 // also drains weight DMA (vmcnt 0)
    } else {
        if (tid == 0) s_count = 0;
        __syncthreads();
        for (int i = tid; i < B_TOK; i += NT) {
            float gv = gate[(size_t)i * N_SAE + e];
            if (gv != 0.0f) {
                int slot = atomicAdd(&s_count, 1);
                if (slot < CAP) { s_tok[slot] = i; s_g[slot] = gv; }
            }
        }
        __syncthreads();
        n = min(s_count, CAP);
    }

    // thread mappings
    const int cq  = tid & 15;          // encode: local col-quad (4*cq .. 4*cq+3)
    const int tg  = (tid >> 4) & 7;    // encode: token pair (2*tg, 2*tg+1)
    const int ds  = tid >> 7;          // encode: d-range half [64*ds, 64*ds+64)
    const int dq  = tid & 31;          // decode: out col-quad (4*dq .. +3)
    const int tgd = tid >> 5;          // decode: token pair (2*tgd, 2*tgd+1)

    float4 be4 = make_float4(0.f, 0.f, 0.f, 0.f);
    if (ds == 0) be4 = ((const float4*)(b_enc + (size_t)e * D_DICT + c * CW))[cq];
    float4 bd4 = make_float4(0.f, 0.f, 0.f, 0.f);
    if (c == 0)  bd4 = ((const float4*)(b_dec + (size_t)e * D_DATA))[dq];

    const float4* We4 = (const float4*)s_We;   // idx d*16 + cq
    const float4* Wd4 = (const float4*)s_Wd;   // idx row*32 + dq
    float4*       X4  = (float4*)s_x;          // idx t*XPITCH + d/4
    float4*       A4  = (float4*)s_acts;       // idx t*16 + ee/4

    for (int t0 = 0; t0 < n; t0 += TILE_T) {
        const int tcnt = min(TILE_T, n - t0);

        // ---- x tile: coalesced float4 loads into padded LDS ----
        for (int i = tid; i < tcnt * 32; i += NT) {
            int tt = i >> 5, col = i & 31;
            X4[tt * XPITCH + col] =
                ((const float4*)(x + (size_t)s_tok[t0 + tt] * D_DATA))[col];
        }
        __syncthreads();

        // ---- encode: partial over d-half; 4 cols x 2 tokens per thread ----
        float4 aA = be4, aB = be4;
        const int tA = 2 * tg, tB = 2 * tg + 1;
        const int dbase = ds * 64;
        #pragma unroll 4
        for (int dd = 0; dd < 64; dd += 4) {
            const int d = dbase + dd;
            float4 w0 = We4[(d + 0) * 16 + cq];
            float4 w1 = We4[(d + 1) * 16 + cq];
            float4 w2 = We4[(d + 2) * 16 + cq];
            float4 w3 = We4[(d + 3) * 16 + cq];
            float4 xa = X4[tA * XPITCH + (d >> 2)];
            float4 xb = X4[tB * XPITCH + (d >> 2)];
            fma4(aA, xa.x, w0); fma4(aA, xa.y, w1); fma4(aA, xa.z, w2); fma4(aA, xa.w, w3);
            fma4(aB, xb.x, w0); fma4(aB, xb.y, w1); fma4(aB, xb.z, w2); fma4(aB, xb.w, w3);
        }
        __syncthreads();

        // ---- reduce the 2 d-halves via LDS (reuse s_x region) ----
        float4* SP = X4;
        const int p = tid & 127;
        if (ds == 1) { SP[p] = aA; SP[128 + p] = aB; }
        __syncthreads();
        if (ds == 0) {
            float4 pA = SP[p], pB = SP[128 + p];
            aA.x += pA.x; aA.y += pA.y; aA.z += pA.z; aA.w += pA.w;
            aB.x += pB.x; aB.y += pB.y; aB.z += pB.z; aB.w += pB.w;
            if (tA < tcnt) {
                float g = s_g[t0 + tA];
                float4 r;
                r.x = fmaxf(aA.x, 0.f) * g; r.y = fmaxf(aA.y, 0.f) * g;
                r.z = fmaxf(aA.z, 0.f) * g; r.w = fmaxf(aA.w, 0.f) * g;
                A4[tA * 16 + cq] = r;
            }
            if (tB < tcnt) {
                float g = s_g[t0 + tB];
                float4 r;
                r.x = fmaxf(aB.x, 0.f) * g; r.y = fmaxf(aB.y, 0.f) * g;
                r.z = fmaxf(aB.z, 0.f) * g; r.w = fmaxf(aB.w, 0.f) * g;
                A4[tB * 16 + cq] = r;
            }
        }
        __syncthreads();

        // ---- decode: 4 out cols x 2 tokens per thread over CW dict rows ----
        float4 oA = make_float4(0.f, 0.f, 0.f, 0.f), oB = oA;
        const int uA = 2 * tgd, uB = 2 * tgd + 1;
        #pragma unroll 4
        for (int ee = 0; ee < CW; ee += 4) {
            float4 w0 = Wd4[(ee + 0) * 32 + dq];
            float4 w1 = Wd4[(ee + 1) * 32 + dq];
            float4 w2 = Wd4[(ee + 2) * 32 + dq];
            float4 w3 = Wd4[(ee + 3) * 32 + dq];
            float4 sa = A4[uA * 16 + (ee >> 2)];
            float4 sb = A4[uB * 16 + (ee >> 2)];
            fma4(oA, sa.x, w0); fma4(oA, sa.y, w1); fma4(oA, sa.z, w2); fma4(oA, sa.w, w3);
            fma4(oB, sb.x, w0); fma4(oB, sb.y, w1); fma4(oB, sb.z, w2); fma4(oB, sb.w, w3);
        }
        if (uA < tcnt) {
            float* op = out + (size_t)s_tok[t0 + uA] * D_DATA + 4 * dq;
            atomicAdd(op + 0, oA.x + bd4.x); atomicAdd(op + 1, oA.y + bd4.y);
            atomicAdd(op + 2, oA.z + bd4.z); atomicAdd(op + 3, oA.w + bd4.w);
        }
        if (uB < tcnt) {
            float* op = out + (size_t)s_tok[t0 + uB] * D_DATA + 4 * dq;
            atomicAdd(op + 0, oB.x + bd4.x); atomicAdd(op + 1, oB.y + bd4.y);
            atomicAdd(op + 2, oB.z + bd4.z); atomicAdd(op + 3, oB.w + bd4.w);
        }
        __syncthreads();   // protect s_x / s_acts for next tile
    }
}

extern "C" void kernel_launch(void* const* d_in, const int* in_sizes, int n_in,
                              void* d_out, int out_size, void* d_ws, size_t ws_size,
                              hipStream_t stream) {
    const float* x     = (const float*)d_in[0];
    const float* gate  = (const float*)d_in[1];
    const float* W_enc = (const float*)d_in[2];
    const float* W_dec = (const float*)d_in[3];
    const float* b_enc = (const float*)d_in[4];
    const float* b_dec = (const float*)d_in[5];
    float* out = (float*)d_out;

    // ws layout: counts[128] int | toks[128*CAP] int | gvs[128*CAP] float
    const size_t ws_needed = N_SAE * sizeof(int)
                           + (size_t)N_SAE * CAP * (sizeof(int) + sizeof(float));
    int use_route = (ws_size >= ws_needed) ? 1 : 0;

    int*   counts = (int*)d_ws;
    int*   toks   = counts + N_SAE;
    float* gvs    = (float*)(toks + (size_t)N_SAE * CAP);

    // d_out is poisoned (0xAA) before every timed launch; we accumulate into it.
    hipMemsetAsync(d_out, 0, (size_t)out_size * sizeof(float), stream);

    if (use_route) {
        hipMemsetAsync(counts, 0, N_SAE * sizeof(int), stream);
        route_kernel<<<B_TOK / 2, NT, 0, stream>>>(gate, counts, toks, gvs);
    }

    dim3 grid(N_SAE, NCHUNK);
    moe_sae_kernel<<<grid, NT, 0, stream>>>(x, gate, W_enc, W_dec, b_enc, b_dec, out,
                                            counts, toks, gvs, use_route);
}

// Round 6
// 126.837 us; speedup vs baseline: 1.2654x; 1.1578x over previous
//
#include <hip/hip_runtime.h>
#include <stdint.h>

// Problem constants (fixed by the reference).
constexpr int N_SAE  = 128;
constexpr int D_DATA = 128;
constexpr int D_DICT = 512;
constexpr int B_TOK  = 1024;

constexpr int NCHUNK = 8;                // dict-dim chunks per expert (weights read once)
constexpr int CW     = D_DICT / NCHUNK;  // 64 dict cols per block
constexpr int NT     = 256;              // 4 waves
constexpr int TILE   = 16;               // tokens per MFMA tile (M=16)
constexpr int CAP    = 64;               // max tokens per expert (mean 16)
constexpr int APITCH = 66;               // s_acts row pitch in floats (even; breaks bank aliasing)

typedef __attribute__((ext_vector_type(8))) short short8;   // 8 x bf16 (4 VGPRs)
typedef __attribute__((ext_vector_type(4))) float f32x4;

__device__ __forceinline__ short f2bf(float f) {
    union { float f; uint32_t u; } v; v.f = f;
    uint32_t u = v.u;
    u += 0x7fffu + ((u >> 16) & 1u);     // round-to-nearest-even
    return (short)(u >> 16);
}

// ---- Routing precompute: coalesced gate scan -> per-expert token lists ----
__global__ __launch_bounds__(NT)
void route_kernel(const float* __restrict__ gate,
                  int* __restrict__ counts,   // [N_SAE]
                  int* __restrict__ toks,     // [N_SAE][CAP]
                  float* __restrict__ gvs)    // [N_SAE][CAP]
{
    const int t = blockIdx.x * 2 + (threadIdx.x >> 7);
    const int e = threadIdx.x & 127;
    float g = gate[(size_t)t * N_SAE + e];    // fully coalesced
    if (g != 0.0f) {
        int slot = atomicAdd(&counts[e], 1);
        if (slot < CAP) {
            toks[e * CAP + slot] = t;
            gvs[e * CAP + slot]  = g;
        }
    }
}

__global__ __launch_bounds__(NT, 4)
void moe_sae_kernel(const float* __restrict__ x,
                    const float* __restrict__ gate,
                    const float* __restrict__ W_enc,
                    const float* __restrict__ W_dec,
                    const float* __restrict__ b_enc,
                    const float* __restrict__ b_dec,
                    float* __restrict__ out,
                    const int* __restrict__ counts,
                    const int* __restrict__ toks,
                    const float* __restrict__ gvs,
                    int use_route)
{
    const int e    = blockIdx.x;     // expert
    const int c    = blockIdx.y;     // dict chunk (64 cols)
    const int tid  = threadIdx.x;
    const int lane = tid & 63;
    const int w    = tid >> 6;       // wave id = encode col-tile
    const int lo   = lane & 15;      // MFMA m/n index
    const int q    = lane >> 4;      // MFMA quad (k group)

    __shared__ float s_acts[TILE * APITCH];  // ~4.2 KB
    __shared__ int   s_tok[CAP];
    __shared__ float s_g[CAP];
    __shared__ int   s_count;

    // ---- Encode B-fragments (We): global f32 -> bf16 VGPR, read once ----
    // B-frag layout: lane holds B[k = q*8+j][n = lo]; ct = w.
    short8 fWe[4];
    {
        const float* We = W_enc + (size_t)e * D_DATA * D_DICT
                        + (size_t)c * CW + w * 16 + lo;
        #pragma unroll
        for (int kb = 0; kb < 4; ++kb) {
            #pragma unroll
            for (int j = 0; j < 8; ++j) {
                int d = kb * 32 + q * 8 + j;
                fWe[kb][j] = f2bf(We[(size_t)d * D_DICT]);
            }
        }
    }
    // ---- Decode B-fragments (Wd): wave w covers out col-tiles {2w, 2w+1} ----
    short8 fWd[2][2];
    {
        #pragma unroll
        for (int s = 0; s < 2; ++s) {
            const float* Wd = W_dec + ((size_t)e * D_DICT + c * CW) * D_DATA
                            + (2 * w + s) * 16 + lo;
            #pragma unroll
            for (int kb = 0; kb < 2; ++kb) {
                #pragma unroll
                for (int j = 0; j < 8; ++j) {
                    int er = kb * 32 + q * 8 + j;
                    fWd[s][kb][j] = f2bf(Wd[(size_t)er * D_DATA]);
                }
            }
        }
    }

    const float be = b_enc[(size_t)e * D_DICT + c * CW + w * 16 + lo];
    float bdv[2] = {0.f, 0.f};
    if (c == 0) {
        bdv[0] = b_dec[(size_t)e * D_DATA + (2 * w + 0) * 16 + lo];
        bdv[1] = b_dec[(size_t)e * D_DATA + (2 * w + 1) * 16 + lo];
    }

    // ---- Routing lists (zero-padded so garbage rows compute finite zeros) ----
    int n;
    if (use_route) {
        n = min(counts[e], CAP);
        if (tid < CAP) {
            s_tok[tid] = (tid < n) ? toks[e * CAP + tid] : 0;
            s_g[tid]   = (tid < n) ? gvs[e * CAP + tid]  : 0.f;
        }
        __syncthreads();
    } else {
        if (tid == 0) s_count = 0;
        __syncthreads();
        for (int i = tid; i < B_TOK; i += NT) {
            float gv = gate[(size_t)i * N_SAE + e];
            if (gv != 0.0f) {
                int slot = atomicAdd(&s_count, 1);
                if (slot < CAP) { s_tok[slot] = i; s_g[slot] = gv; }
            }
        }
        __syncthreads();
        n = min(s_count, CAP);
        if (tid >= n && tid < CAP) { s_tok[tid] = 0; s_g[tid] = 0.f; }
        __syncthreads();
    }
    if (n == 0) return;

    for (int t0 = 0; t0 < n; t0 += TILE) {
        // ---- x A-fragments: lane m = lo -> token slot t0+lo (clamped) ----
        short8 fx[4];
        {
            int slot = t0 + lo;
            if (slot >= n) slot = n - 1;
            const float* xr = x + (size_t)s_tok[slot] * D_DATA;
            #pragma unroll
            for (int kb = 0; kb < 4; ++kb) {
                #pragma unroll
                for (int j = 0; j < 8; j += 2) {
                    float2 v = *(const float2*)&xr[kb * 32 + q * 8 + j];
                    fx[kb][j]     = f2bf(v.x);
                    fx[kb][j + 1] = f2bf(v.y);
                }
            }
        }

        // ---- encode: acts[16 tok x 16 cols] per wave, K = 128 ----
        f32x4 acc = {be, be, be, be};
        #pragma unroll
        for (int kb = 0; kb < 4; ++kb)
            acc = __builtin_amdgcn_mfma_f32_16x16x32_bf16(fx[kb], fWe[kb], acc, 0, 0, 0);

        // C-layout: col = lo (+w*16), row = q*4 + r.  relu * g, store to LDS.
        #pragma unroll
        for (int r = 0; r < 4; ++r) {
            int row = q * 4 + r;
            float g = s_g[t0 + row];                       // broadcast (16 lanes same addr)
            s_acts[row * APITCH + w * 16 + lo] = fmaxf(acc[r], 0.f) * g;
        }
        __syncthreads();

        // ---- decode A-fragments from s_acts: m = lo (token), k = e-local ----
        short8 fa[2];
        #pragma unroll
        for (int kb = 0; kb < 2; ++kb) {
            #pragma unroll
            for (int j = 0; j < 8; j += 2) {
                float2 v = *(const float2*)&s_acts[lo * APITCH + kb * 32 + q * 8 + j];
                fa[kb][j]     = f2bf(v.x);
                fa[kb][j + 1] = f2bf(v.y);
            }
        }

        // ---- decode: out[16 tok x 16 cols] per col-tile, K = 64 ----
        #pragma unroll
        for (int s = 0; s < 2; ++s) {
            f32x4 oc = {bdv[s], bdv[s], bdv[s], bdv[s]};
            #pragma unroll
            for (int kb = 0; kb < 2; ++kb)
                oc = __builtin_amdgcn_mfma_f32_16x16x32_bf16(fa[kb], fWd[s][kb], oc, 0, 0, 0);
            #pragma unroll
            for (int r = 0; r < 4; ++r) {
                int row = q * 4 + r;
                if (t0 + row < n)
                    atomicAdd(&out[(size_t)s_tok[t0 + row] * D_DATA + (2 * w + s) * 16 + lo],
                              oc[r]);
            }
        }
        __syncthreads();   // s_acts reused next tile
    }
}

extern "C" void kernel_launch(void* const* d_in, const int* in_sizes, int n_in,
                              void* d_out, int out_size, void* d_ws, size_t ws_size,
                              hipStream_t stream) {
    const float* x     = (const float*)d_in[0];
    const float* gate  = (const float*)d_in[1];
    const float* W_enc = (const float*)d_in[2];
    const float* W_dec = (const float*)d_in[3];
    const float* b_enc = (const float*)d_in[4];
    const float* b_dec = (const float*)d_in[5];
    float* out = (float*)d_out;

    // ws layout: counts[128] int | toks[128*CAP] int | gvs[128*CAP] float
    const size_t ws_needed = N_SAE * sizeof(int)
                           + (size_t)N_SAE * CAP * (sizeof(int) + sizeof(float));
    int use_route = (ws_size >= ws_needed) ? 1 : 0;

    int*   counts = (int*)d_ws;
    int*   toks   = counts + N_SAE;
    float* gvs    = (float*)(toks + (size_t)N_SAE * CAP);

    // d_out is poisoned (0xAA) before every timed launch; we accumulate into it.
    hipMemsetAsync(d_out, 0, (size_t)out_size * sizeof(float), stream);

    if (use_route) {
        hipMemsetAsync(counts, 0, N_SAE * sizeof(int), stream);
        route_kernel<<<B_TOK / 2, NT, 0, stream>>>(gate, counts, toks, gvs);
    }

    dim3 grid(N_SAE, NCHUNK);
    moe_sae_kernel<<<grid, NT, 0, stream>>>(x, gate, W_enc, W_dec, b_enc, b_dec, out,
                                            counts, toks, gvs, use_route);
}

// Round 7
// 123.291 us; speedup vs baseline: 1.3018x; 1.0288x over previous
//
#include <hip/hip_runtime.h>
#include <stdint.h>

// Problem constants (fixed by the reference).
constexpr int N_SAE  = 128;
constexpr int D_DATA = 128;
constexpr int D_DICT = 512;
constexpr int B_TOK  = 1024;

constexpr int NCHUNK = 8;                // dict-dim chunks per expert (weights read once)
constexpr int CW     = D_DICT / NCHUNK;  // 64 dict cols per block
constexpr int NT     = 256;              // 4 waves
constexpr int TILE   = 16;               // tokens per MFMA tile (M=16)
constexpr int CAP    = 64;               // max tokens per expert (mean 16)
constexpr int APITCH = 66;               // s_acts row pitch in floats

typedef __attribute__((ext_vector_type(8))) short short8;   // 8 x bf16 (4 VGPRs)
typedef __attribute__((ext_vector_type(4))) float f32x4;

__device__ __forceinline__ short f2bf(float f) {
    union { float f; uint32_t u; } v; v.f = f;
    uint32_t u = v.u;
    u += 0x7fffu + ((u >> 16) & 1u);     // round-to-nearest-even
    return (short)(u >> 16);
}

// ---- Routing precompute: coalesced gate scan -> per-expert token lists
// ---- plus inverse map: token -> its 2 (expert*CAP+slot) partial-row bases.
__global__ __launch_bounds__(NT)
void route_kernel(const float* __restrict__ gate,
                  int* __restrict__ counts,   // [N_SAE]
                  int* __restrict__ tcnt,     // [B_TOK]
                  int* __restrict__ inv,      // [B_TOK][2]
                  int* __restrict__ toks,     // [N_SAE][CAP]
                  float* __restrict__ gvs)    // [N_SAE][CAP]
{
    const int t = blockIdx.x * 2 + (threadIdx.x >> 7);
    const int e = threadIdx.x & 127;
    float g = gate[(size_t)t * N_SAE + e];    // fully coalesced
    if (g != 0.0f) {
        int slot = atomicAdd(&counts[e], 1);
        if (slot < CAP) {
            toks[e * CAP + slot] = t;
            gvs[e * CAP + slot]  = g;
            int j = atomicAdd(&tcnt[t], 1);   // exactly 2 per token
            if (j < 2) inv[t * 2 + j] = e * CAP + slot;
        }
    }
}

__global__ __launch_bounds__(NT, 4)
void moe_sae_kernel(const float* __restrict__ x,
                    const float* __restrict__ gate,
                    const float* __restrict__ W_enc,
                    const float* __restrict__ W_dec,
                    const float* __restrict__ b_enc,
                    const float* __restrict__ b_dec,
                    float* __restrict__ out,
                    float* __restrict__ P,        // [N_SAE*CAP][NCHUNK][D_DATA]
                    const int* __restrict__ counts,
                    const int* __restrict__ toks,
                    const float* __restrict__ gvs,
                    int use_part)
{
    const int e    = blockIdx.x;     // expert
    const int c    = blockIdx.y;     // dict chunk (64 cols)
    const int tid  = threadIdx.x;
    const int lane = tid & 63;
    const int w    = tid >> 6;       // wave id = encode col-tile
    const int lo   = lane & 15;      // MFMA m/n index
    const int q    = lane >> 4;      // MFMA quad (k group)

    __shared__ float s_acts[TILE * APITCH];  // ~4.2 KB
    __shared__ int   s_tok[CAP];
    __shared__ float s_g[CAP];
    __shared__ int   s_count;

    // ---- Encode B-fragments (We): global f32 -> bf16 VGPR, read once ----
    short8 fWe[4];
    {
        const float* We = W_enc + (size_t)e * D_DATA * D_DICT
                        + (size_t)c * CW + w * 16 + lo;
        #pragma unroll
        for (int kb = 0; kb < 4; ++kb) {
            #pragma unroll
            for (int j = 0; j < 8; ++j) {
                int d = kb * 32 + q * 8 + j;
                fWe[kb][j] = f2bf(We[(size_t)d * D_DICT]);
            }
        }
    }
    // ---- Decode B-fragments (Wd): wave w covers out col-tiles {2w, 2w+1} ----
    short8 fWd[2][2];
    {
        #pragma unroll
        for (int s = 0; s < 2; ++s) {
            const float* Wd = W_dec + ((size_t)e * D_DICT + c * CW) * D_DATA
                            + (2 * w + s) * 16 + lo;
            #pragma unroll
            for (int kb = 0; kb < 2; ++kb) {
                #pragma unroll
                for (int j = 0; j < 8; ++j) {
                    int er = kb * 32 + q * 8 + j;
                    fWd[s][kb][j] = f2bf(Wd[(size_t)er * D_DATA]);
                }
            }
        }
    }

    const float be = b_enc[(size_t)e * D_DICT + c * CW + w * 16 + lo];
    float bdv[2] = {0.f, 0.f};
    if (c == 0) {
        bdv[0] = b_dec[(size_t)e * D_DATA + (2 * w + 0) * 16 + lo];
        bdv[1] = b_dec[(size_t)e * D_DATA + (2 * w + 1) * 16 + lo];
    }

    // ---- Routing lists (zero-padded so garbage rows compute finite zeros) ----
    int n;
    if (use_part) {
        n = min(counts[e], CAP);
        if (tid < CAP) {
            s_tok[tid] = (tid < n) ? toks[e * CAP + tid] : 0;
            s_g[tid]   = (tid < n) ? gvs[e * CAP + tid]  : 0.f;
        }
        __syncthreads();
    } else {
        if (tid == 0) s_count = 0;
        __syncthreads();
        for (int i = tid; i < B_TOK; i += NT) {
            float gv = gate[(size_t)i * N_SAE + e];
            if (gv != 0.0f) {
                int slot = atomicAdd(&s_count, 1);
                if (slot < CAP) { s_tok[slot] = i; s_g[slot] = gv; }
            }
        }
        __syncthreads();
        n = min(s_count, CAP);
        if (tid >= n && tid < CAP) { s_tok[tid] = 0; s_g[tid] = 0.f; }
        __syncthreads();
    }
    if (n == 0) return;

    for (int t0 = 0; t0 < n; t0 += TILE) {
        // ---- x A-fragments: lane m = lo -> token slot t0+lo (clamped) ----
        short8 fx[4];
        {
            int slot = t0 + lo;
            if (slot >= n) slot = n - 1;
            const float* xr = x + (size_t)s_tok[slot] * D_DATA;
            #pragma unroll
            for (int kb = 0; kb < 4; ++kb) {
                #pragma unroll
                for (int j = 0; j < 8; j += 2) {
                    float2 v = *(const float2*)&xr[kb * 32 + q * 8 + j];
                    fx[kb][j]     = f2bf(v.x);
                    fx[kb][j + 1] = f2bf(v.y);
                }
            }
        }

        // ---- encode: acts[16 tok x 16 cols] per wave, K = 128 ----
        f32x4 acc = {be, be, be, be};
        #pragma unroll
        for (int kb = 0; kb < 4; ++kb)
            acc = __builtin_amdgcn_mfma_f32_16x16x32_bf16(fx[kb], fWe[kb], acc, 0, 0, 0);

        // C-layout: col = lo (+w*16), row = q*4 + r.  relu * g, store to LDS.
        #pragma unroll
        for (int r = 0; r < 4; ++r) {
            int row = q * 4 + r;
            float g = s_g[t0 + row];
            s_acts[row * APITCH + w * 16 + lo] = fmaxf(acc[r], 0.f) * g;
        }
        __syncthreads();

        // ---- decode A-fragments from s_acts: m = lo (token), k = e-local ----
        short8 fa[2];
        #pragma unroll
        for (int kb = 0; kb < 2; ++kb) {
            #pragma unroll
            for (int j = 0; j < 8; j += 2) {
                float2 v = *(const float2*)&s_acts[lo * APITCH + kb * 32 + q * 8 + j];
                fa[kb][j]     = f2bf(v.x);
                fa[kb][j + 1] = f2bf(v.y);
            }
        }

        // ---- decode: out[16 tok x 16 cols] per col-tile, K = 64 ----
        #pragma unroll
        for (int s = 0; s < 2; ++s) {
            f32x4 oc = {bdv[s], bdv[s], bdv[s], bdv[s]};
            #pragma unroll
            for (int kb = 0; kb < 2; ++kb)
                oc = __builtin_amdgcn_mfma_f32_16x16x32_bf16(fa[kb], fWd[s][kb], oc, 0, 0, 0);
            if (use_part) {
                #pragma unroll
                for (int r = 0; r < 4; ++r) {
                    int row = q * 4 + r;
                    int slot = t0 + row;
                    if (slot < n)
                        P[(((size_t)e * CAP + slot) * NCHUNK + c) * D_DATA
                          + (2 * w + s) * 16 + lo] = oc[r];
                }
            } else {
                #pragma unroll
                for (int r = 0; r < 4; ++r) {
                    int row = q * 4 + r;
                    if (t0 + row < n)
                        atomicAdd(&out[(size_t)s_tok[t0 + row] * D_DATA
                                       + (2 * w + s) * 16 + lo], oc[r]);
                }
            }
        }
        __syncthreads();   // s_acts reused next tile
    }
}

// ---- Final reduce: per token sum its 2 experts x 8 chunks of partials ----
__global__ __launch_bounds__(NT)
void reduce_kernel(const float* __restrict__ P,
                   const int* __restrict__ inv,
                   const int* __restrict__ tcnt,
                   float* __restrict__ out)
{
    const int t   = blockIdx.x * 2 + (threadIdx.x >> 7);
    const int col = threadIdx.x & 127;
    float s = 0.f;
    int m = min(tcnt[t], 2);
    for (int j = 0; j < m; ++j) {
        const float* p = P + (size_t)inv[t * 2 + j] * NCHUNK * D_DATA + col;
        #pragma unroll
        for (int c = 0; c < NCHUNK; ++c) s += p[(size_t)c * D_DATA];
    }
    out[(size_t)t * D_DATA + col] = s;
}

extern "C" void kernel_launch(void* const* d_in, const int* in_sizes, int n_in,
                              void* d_out, int out_size, void* d_ws, size_t ws_size,
                              hipStream_t stream) {
    const float* x     = (const float*)d_in[0];
    const float* gate  = (const float*)d_in[1];
    const float* W_enc = (const float*)d_in[2];
    const float* W_dec = (const float*)d_in[3];
    const float* b_enc = (const float*)d_in[4];
    const float* b_dec = (const float*)d_in[5];
    float* out = (float*)d_out;

    // ws layout (ints/floats are 4 B):
    //   counts[128] | tcnt[1024] | inv[2048] | toks[128*CAP] | gvs[128*CAP] | P[128*CAP*8*128]
    int*   counts = (int*)d_ws;
    int*   tcnt   = counts + N_SAE;
    int*   inv    = tcnt + B_TOK;
    int*   toks   = inv + 2 * B_TOK;
    float* gvs    = (float*)(toks + (size_t)N_SAE * CAP);
    float* P      = gvs + (size_t)N_SAE * CAP;
    const size_t ws_needed = (size_t)(N_SAE + B_TOK + 2 * B_TOK + 2 * N_SAE * CAP) * 4
                           + (size_t)N_SAE * CAP * NCHUNK * D_DATA * 4;
    int use_part = (ws_size >= ws_needed) ? 1 : 0;

    if (use_part) {
        // zero counts + tcnt in one shot (contiguous)
        hipMemsetAsync(counts, 0, (size_t)(N_SAE + B_TOK) * sizeof(int), stream);
        route_kernel<<<B_TOK / 2, NT, 0, stream>>>(gate, counts, tcnt, inv, toks, gvs);
    } else {
        // fallback: atomic accumulation straight into d_out
        hipMemsetAsync(d_out, 0, (size_t)out_size * sizeof(float), stream);
    }

    dim3 grid(N_SAE, NCHUNK);
    moe_sae_kernel<<<grid, NT, 0, stream>>>(x, gate, W_enc, W_dec, b_enc, b_dec, out,
                                            P, counts, toks, gvs, use_part);

    if (use_part)
        reduce_kernel<<<B_TOK / 2, NT, 0, stream>>>(P, inv, tcnt, out);
}